// Round 23
// baseline (2050.313 us; speedup 1.0000x reference)
//
#include <hip/hip_runtime.h>
#include <hip/hip_bf16.h>

#define B_ 64
#define T_ 2048
#define DIN_ 128
#define H_ 256
#define DOUT_ 128
#define CH_ 512   // T-chunk per pipelined launch (4 chunks)

typedef __bf16 bf16x8 __attribute__((ext_vector_type(8)));
typedef unsigned short u16x8 __attribute__((ext_vector_type(8)));
typedef unsigned int u32x2 __attribute__((ext_vector_type(2)));
typedef unsigned int u32x4 __attribute__((ext_vector_type(4)));
typedef float f32x4 __attribute__((ext_vector_type(4)));

// LDS-only barrier (validated R19): orders LDS without draining vmcnt ->
// global stores/prefetch loads stay in flight across steps.
#define BAR_LDS() asm volatile("s_waitcnt lgkmcnt(0)\n\ts_barrier" ::: "memory")

static __device__ __forceinline__ unsigned short f2bf(float f) {
    union { float f; unsigned u; } v; v.f = f;
    unsigned r = v.u + 0x7FFFu + ((v.u >> 16) & 1u);   // RNE
    return (unsigned short)(r >> 16);
}
static __device__ __forceinline__ unsigned cvt_pk_bf16(float lo, float hi) {
    unsigned r;
    asm("v_cvt_pk_bf16_f32 %0, %1, %2" : "=v"(r) : "v"(lo), "v"(hi));
    return r;
}
static __device__ __forceinline__ float bfbits_lo(unsigned w) {
    union { unsigned u; float f; } v; v.u = w << 16; return v.f;
}
static __device__ __forceinline__ float bfbits_hi(unsigned w) {
    union { unsigned u; float f; } v; v.u = w & 0xFFFF0000u; return v.f;
}
static __device__ __forceinline__ float tanh_fast(float x) {
    float e = __builtin_amdgcn_exp2f(2.885390081777927f * x);
    float r = __builtin_amdgcn_rcpf(e + 1.0f);
    return __builtin_fmaf(-2.0f, r, 1.0f);
}
static __device__ __forceinline__ bf16x8 ld8f_bf(const float* p) {
    float4 a = *(const float4*)p;
    float4 b = *(const float4*)(p + 4);
    u32x4 u;
    u[0] = cvt_pk_bf16(a.x, a.y);
    u[1] = cvt_pk_bf16(a.z, a.w);
    u[2] = cvt_pk_bf16(b.x, b.y);
    u[3] = cvt_pk_bf16(b.z, b.w);
    return __builtin_bit_cast(bf16x8, u);
}

// -------- kernel 1 (swapped): Pre0[t][b][n] = b0[n] + sum_k x[b][t][k]*Wx0[n][k]
__global__ __launch_bounds__(256) void k_pre(const float* __restrict__ x,
                                             const float* __restrict__ Wx0,
                                             const float* __restrict__ b0,
                                             unsigned short* __restrict__ Pre0) {
    const int t  = blockIdx.x;
    const int bc = blockIdx.y;
    const int w  = threadIdx.x >> 6;
    const int l  = threadIdx.x & 63;
    const int lr = l & 15, lg = l >> 4;

    bf16x8 af[4];
    const float* xrow = x + ((size_t)(bc * 16 + lr) * T_ + t) * DIN_ + lg * 8;
#pragma unroll
    for (int kk = 0; kk < 4; kk++) af[kk] = ld8f_bf(xrow + kk * 32);

    unsigned short* op = Pre0 + ((size_t)t * B_ + bc * 16 + lr) * H_;

#pragma unroll
    for (int i = 0; i < 4; i++) {
        const int n0 = (w + 4 * i) * 16;
        const float* wrow = Wx0 + (size_t)(n0 + lr) * DIN_ + lg * 8;
        bf16x8 bfr[4];
#pragma unroll
        for (int kk = 0; kk < 4; kk++) bfr[kk] = ld8f_bf(wrow + kk * 32);
        float4 bv = *(const float4*)&b0[n0 + lg * 4];
        f32x4 acc = { bv.x, bv.y, bv.z, bv.w };
#pragma unroll
        for (int kk = 0; kk < 4; kk++)
            acc = __builtin_amdgcn_mfma_f32_16x16x32_bf16(bfr[kk], af[kk], acc, 0, 0, 0);
        u32x2 pk;
        pk[0] = cvt_pk_bf16(acc[0], acc[1]);
        pk[1] = cvt_pk_bf16(acc[2], acc[3]);
        *(u32x2*)&op[n0 + lg * 4] = pk;
    }
}

// ---- scan0 body: layer-0 recurrence over t in [t0,t1). 8 waves x 32 n,
// M=1 broadcast-LDS. Initial state from h0in (t0==0) or the h0n stream.
static __device__ void scan0_body(int b, int tid,
                                  const float* __restrict__ h0in,
                                  const float* __restrict__ Wh0,
                                  const unsigned short* __restrict__ Pre0,
                                  unsigned short* __restrict__ h0n,
                                  int t0, int t1) {
    __shared__ __align__(16) unsigned short h0s[2][256];

    const int w  = tid >> 6, l = tid & 63;
    const int lr = l & 15, lg = l >> 4;
    const int n0 = w * 32;

    bf16x8 wh0f[2][8];   // W[n0+u*16+lr][kk*32+lg*8 .. +7]
#pragma unroll
    for (int u = 0; u < 2; u++) {
        const int n = n0 + u * 16 + lr;
#pragma unroll
        for (int kk = 0; kk < 8; kk++)
            wh0f[u][kk] = ld8f_bf(Wh0 + (size_t)n * H_ + kk * 32 + lg * 8);
    }

    if (tid < 256)
        h0s[0][tid] = (t0 == 0) ? f2bf(h0in[(size_t)b * H_ + tid])
                                : h0n[((size_t)b * T_ + t0 - 1) * H_ + tid];

    const unsigned short* prep = Pre0 + ((size_t)t0 * B_ + b) * H_ + n0 + lg * 4;
    u32x2 pv[2];
#pragma unroll
    for (int u = 0; u < 2; u++) pv[u] = *(const u32x2*)(prep + u * 16);
    prep += B_ * H_;

    unsigned short* op = h0n + ((size_t)b * T_ + t0) * H_ + n0 + lg * 4;

    __syncthreads();

    int cur = 0;
    for (int t = t0; t < t1; t++) {
        const int nxt = cur ^ 1;
        f32x4 a[2][2];   // [n-tile][k-half]
#pragma unroll
        for (int u = 0; u < 2; u++) {
            a[u][0][0] = bfbits_lo(pv[u][0]); a[u][0][1] = bfbits_hi(pv[u][0]);
            a[u][0][2] = bfbits_lo(pv[u][1]); a[u][0][3] = bfbits_hi(pv[u][1]);
            a[u][1] = (f32x4){0.0f, 0.0f, 0.0f, 0.0f};
        }
        // prefetch next Pre0 (over-read at t1-1 stays outside concurrent writers)
#pragma unroll
        for (int u = 0; u < 2; u++) pv[u] = *(const u32x2*)(prep + u * 16);
        prep += B_ * H_;
#pragma unroll
        for (int kk = 0; kk < 4; kk++) {
            bf16x8 s0 = __builtin_bit_cast(bf16x8, *(const u16x8*)&h0s[cur][kk * 32 + lg * 8]);
            bf16x8 s1 = __builtin_bit_cast(bf16x8, *(const u16x8*)&h0s[cur][(kk + 4) * 32 + lg * 8]);
#pragma unroll
            for (int u = 0; u < 2; u++) {
                a[u][0] = __builtin_amdgcn_mfma_f32_16x16x32_bf16(wh0f[u][kk],     s0, a[u][0], 0, 0, 0);
                a[u][1] = __builtin_amdgcn_mfma_f32_16x16x32_bf16(wh0f[u][kk + 4], s1, a[u][1], 0, 0, 0);
            }
        }
#pragma unroll
        for (int u = 0; u < 2; u++) {
            f32x4 h = a[u][0] + a[u][1];
            u32x2 pk;
            pk[0] = cvt_pk_bf16(tanh_fast(h[0]), tanh_fast(h[1]));
            pk[1] = cvt_pk_bf16(tanh_fast(h[2]), tanh_fast(h[3]));
            if (lr == 0) {
                *(u32x2*)&h0s[nxt][n0 + u * 16 + lg * 4] = pk;
                *(u32x2*)(op + u * 16) = pk;
            }
        }
        op += H_;
        BAR_LDS();
        cur = nxt;
    }
}

// ---- scan1 body: time-batched P1 + layer-1 recurrence over t in [t0,t1).
// Initial h1 from h0in (t0==0) or the H1 stream (bf16, bit-identical).
static __device__ void scan1_body(int b, int tid,
                                  const float* __restrict__ h0in,
                                  const float* __restrict__ Wx1,
                                  const float* __restrict__ Wh1,
                                  const float* __restrict__ b1,
                                  const unsigned short* __restrict__ h0n,
                                  unsigned short* __restrict__ H1,
                                  int t0, int t1) {
    __shared__ __align__(16) unsigned short h1s[2][256];
    __shared__ __align__(16) float p1lds[16][264];

    const int w  = tid >> 6, l = tid & 63;
    const int lr = l & 15, lg = l >> 4;
    const int n0 = w * 32;

    bf16x8 wx1f[2][8], wh1f[2][8];
#pragma unroll
    for (int u = 0; u < 2; u++) {
        const int n = n0 + u * 16 + lr;
#pragma unroll
        for (int kk = 0; kk < 8; kk++) {
            wx1f[u][kk] = ld8f_bf(Wx1 + (size_t)n * H_ + kk * 32 + lg * 8);
            wh1f[u][kk] = ld8f_bf(Wh1 + (size_t)n * H_ + kk * 32 + lg * 8);
        }
    }
    float4 b1q[2];
#pragma unroll
    for (int u = 0; u < 2; u++) b1q[u] = *(const float4*)&b1[n0 + u * 16 + lg * 4];

    if (tid < 256)
        h1s[0][tid] = (t0 == 0) ? f2bf(h0in[(size_t)(B_ + b) * H_ + tid])
                                : H1[((size_t)(t0 - 1) * B_ + b) * H_ + tid];

    const unsigned short* hp = h0n + (size_t)b * T_ * H_;
    unsigned short* yp = H1 + (size_t)b * H_ + n0 + lg * 4;

    __syncthreads();

    int cur = 0;
    for (int tc = t0 / 16; tc < t1 / 16; tc++) {
        // ---- phase A: p1 tile (32 n x 16 t) for this wave
        f32x4 p[2][2];
#pragma unroll
        for (int u = 0; u < 2; u++) {
            p[u][0] = (f32x4){ b1q[u].x, b1q[u].y, b1q[u].z, b1q[u].w };
            p[u][1] = (f32x4){0.0f, 0.0f, 0.0f, 0.0f};
        }
        const unsigned short* hrow = hp + (size_t)(tc * 16 + lr) * H_ + lg * 8;
#pragma unroll
        for (int kk = 0; kk < 4; kk++) {
            bf16x8 s0 = __builtin_bit_cast(bf16x8, *(const u16x8*)(hrow + kk * 32));
            bf16x8 s1 = __builtin_bit_cast(bf16x8, *(const u16x8*)(hrow + (kk + 4) * 32));
#pragma unroll
            for (int u = 0; u < 2; u++) {
                p[u][0] = __builtin_amdgcn_mfma_f32_16x16x32_bf16(wx1f[u][kk],     s0, p[u][0], 0, 0, 0);
                p[u][1] = __builtin_amdgcn_mfma_f32_16x16x32_bf16(wx1f[u][kk + 4], s1, p[u][1], 0, 0, 0);
            }
        }
#pragma unroll
        for (int u = 0; u < 2; u++) {
            f32x4 pp = p[u][0] + p[u][1];
            *(f32x4*)&p1lds[lr][n0 + u * 16 + lg * 4] = pp;
        }
        // no barrier: each wave reads back only its own columns

        // ---- phase B: 16 sequential layer-1 steps
        for (int ti = 0; ti < 16; ti++) {
            const int nxt = cur ^ 1;
            f32x4 d[2][2];
#pragma unroll
            for (int u = 0; u < 2; u++) {
                d[u][0] = *(const f32x4*)&p1lds[ti][n0 + u * 16 + lg * 4];
                d[u][1] = (f32x4){0.0f, 0.0f, 0.0f, 0.0f};
            }
#pragma unroll
            for (int kk = 0; kk < 4; kk++) {
                bf16x8 s0 = __builtin_bit_cast(bf16x8, *(const u16x8*)&h1s[cur][kk * 32 + lg * 8]);
                bf16x8 s1 = __builtin_bit_cast(bf16x8, *(const u16x8*)&h1s[cur][(kk + 4) * 32 + lg * 8]);
#pragma unroll
                for (int u = 0; u < 2; u++) {
                    d[u][0] = __builtin_amdgcn_mfma_f32_16x16x32_bf16(wh1f[u][kk],     s0, d[u][0], 0, 0, 0);
                    d[u][1] = __builtin_amdgcn_mfma_f32_16x16x32_bf16(wh1f[u][kk + 4], s1, d[u][1], 0, 0, 0);
                }
            }
#pragma unroll
            for (int u = 0; u < 2; u++) {
                f32x4 hh = d[u][0] + d[u][1];
                u32x2 pk;
                pk[0] = cvt_pk_bf16(tanh_fast(hh[0]), tanh_fast(hh[1]));
                pk[1] = cvt_pk_bf16(tanh_fast(hh[2]), tanh_fast(hh[3]));
                if (lr == 0) {
                    *(u32x2*)&h1s[nxt][n0 + u * 16 + lg * 4] = pk;
                    *(u32x2*)(yp + (size_t)(tc * 16 + ti) * B_ * H_ + u * 16) = pk;
                }
            }
            BAR_LDS();
            cur = nxt;
        }
    }
}

// -------- kernel 2: pipelined mixed scan. 128 blocks x 512 threads.
// Blocks 0..63:  scan0 over [s, s+CH)      (producer chunk k)
// Blocks 64..127: scan1 over [s-CH, s)     (consumer chunk k-1)
// Ranges are DISJOINT in Pre0/h0n/H1 -> no races, no fences; the chunk
// dependency is carried by stream-ordered kernel launches.
__global__ __launch_bounds__(512)
void k_scan_mix(const float* __restrict__ h0in,
                const float* __restrict__ Wh0,
                const float* __restrict__ Wx1,
                const float* __restrict__ Wh1,
                const float* __restrict__ b1,
                const unsigned short* __restrict__ Pre0,
                unsigned short* __restrict__ h0n,
                unsigned short* __restrict__ H1,
                int s) {
    const int role = blockIdx.x >> 6;
    const int b    = blockIdx.x & 63;
    const int tid  = threadIdx.x;
    if (role == 0) {
        int t0 = s, t1 = s + CH_;
        if (t0 >= T_) return;
        if (t1 > T_) t1 = T_;
        scan0_body(b, tid, h0in, Wh0, Pre0, h0n, t0, t1);
    } else {
        int t0 = s - CH_, t1 = s;
        if (t1 <= 0) return;
        if (t0 < 0) t0 = 0;
        scan1_body(b, tid, h0in, Wx1, Wh1, b1, h0n, H1, t0, t1);
    }
}

// -------- kernel 3 (swapped): Y[b][t][d] = bout[d] + sum_k H1[t][b][k]*Wout[d][k]
__global__ __launch_bounds__(256) void k_out(const unsigned short* __restrict__ H1,
                                             const float* __restrict__ Wout,
                                             const float* __restrict__ bout,
                                             float* __restrict__ out) {
    const int t  = blockIdx.x;
    const int bc = blockIdx.y;
    const int w  = threadIdx.x >> 6;
    const int l  = threadIdx.x & 63;
    const int lr = l & 15, lg = l >> 4;

    bf16x8 af[8];
    const unsigned short* hrow = H1 + ((size_t)t * B_ + bc * 16 + lr) * H_ + lg * 8;
#pragma unroll
    for (int kk = 0; kk < 8; kk++)
        af[kk] = __builtin_bit_cast(bf16x8, *(const u16x8*)(hrow + kk * 32));

#pragma unroll
    for (int i = 0; i < 2; i++) {
        const int n0 = (w + 4 * i) * 16;
        const float* wrow = Wout + (size_t)(n0 + lr) * H_ + lg * 8;
        float4 bv = *(const float4*)&bout[n0 + lg * 4];
        f32x4 acc = { bv.x, bv.y, bv.z, bv.w };
#pragma unroll
        for (int kk = 0; kk < 8; kk++) {
            bf16x8 bfr = ld8f_bf(wrow + kk * 32);
            acc = __builtin_amdgcn_mfma_f32_16x16x32_bf16(bfr, af[kk], acc, 0, 0, 0);
        }
        *(f32x4*)&out[((size_t)(bc * 16 + lr) * T_ + t) * DOUT_ + n0 + lg * 4] = acc;
    }
}

extern "C" void kernel_launch(void* const* d_in, const int* in_sizes, int n_in,
                              void* d_out, int out_size, void* d_ws, size_t ws_size,
                              hipStream_t stream) {
    const float* x    = (const float*)d_in[0];
    const float* h0   = (const float*)d_in[1];
    const float* Wx0  = (const float*)d_in[2];
    const float* Wh0  = (const float*)d_in[3];
    const float* b0   = (const float*)d_in[4];
    const float* Wx1  = (const float*)d_in[5];
    const float* Wh1  = (const float*)d_in[6];
    const float* b1   = (const float*)d_in[7];
    const float* Wout = (const float*)d_in[8];
    const float* bout = (const float*)d_in[9];
    float* out = (float*)d_out;

    // ws: region A (64MB) = Pre0, progressively overwritten by H1 exactly one
    //     chunk behind the scan0 read front (disjoint per launch).
    //     region B (64MB) = h0n stream [b][t][n] bf16.
    unsigned short* Pre0 = (unsigned short*)d_ws;
    unsigned short* h0n  = Pre0 + (size_t)T_ * B_ * H_;
    unsigned short* H1   = Pre0;

    k_pre<<<dim3(T_, B_ / 16), 256, 0, stream>>>(x, Wx0, b0, Pre0);
    for (int s = 0; s <= T_; s += CH_)
        k_scan_mix<<<dim3(2 * B_), 512, 0, stream>>>(h0, Wh0, Wx1, Wh1, b1,
                                                     Pre0, h0n, H1, s);
    k_out<<<dim3(T_, B_ / 16), 256, 0, stream>>>(H1, Wout, bout, out);
}

// Round 25
// 2040.861 us; speedup vs baseline: 1.0046x; 1.0046x over previous
//
#include <hip/hip_runtime.h>
#include <hip/hip_bf16.h>

#define B_ 64
#define T_ 2048
#define DIN_ 128
#define H_ 256
#define DOUT_ 128
#define CH_ 512   // T-chunk per pipelined launch (4 chunks)

typedef __bf16 bf16x8 __attribute__((ext_vector_type(8)));
typedef unsigned short u16x8 __attribute__((ext_vector_type(8)));
typedef unsigned int u32x2 __attribute__((ext_vector_type(2)));
typedef unsigned int u32x4 __attribute__((ext_vector_type(4)));
typedef float f32x4 __attribute__((ext_vector_type(4)));

// LDS-only barrier (validated R19): orders LDS without draining vmcnt ->
// global stores/prefetch loads stay in flight across steps.
#define BAR_LDS() asm volatile("s_waitcnt lgkmcnt(0)\n\ts_barrier" ::: "memory")

static __device__ __forceinline__ unsigned short f2bf(float f) {
    union { float f; unsigned u; } v; v.f = f;
    unsigned r = v.u + 0x7FFFu + ((v.u >> 16) & 1u);   // RNE
    return (unsigned short)(r >> 16);
}
static __device__ __forceinline__ unsigned cvt_pk_bf16(float lo, float hi) {
    unsigned r;
    asm("v_cvt_pk_bf16_f32 %0, %1, %2" : "=v"(r) : "v"(lo), "v"(hi));
    return r;
}
static __device__ __forceinline__ float bfbits_lo(unsigned w) {
    union { unsigned u; float f; } v; v.u = w << 16; return v.f;
}
static __device__ __forceinline__ float bfbits_hi(unsigned w) {
    union { unsigned u; float f; } v; v.u = w & 0xFFFF0000u; return v.f;
}
static __device__ __forceinline__ float tanh_fast(float x) {
    float e = __builtin_amdgcn_exp2f(2.885390081777927f * x);
    float r = __builtin_amdgcn_rcpf(e + 1.0f);
    return __builtin_fmaf(-2.0f, r, 1.0f);
}
static __device__ __forceinline__ bf16x8 ld8f_bf(const float* p) {
    float4 a = *(const float4*)p;
    float4 b = *(const float4*)(p + 4);
    u32x4 u;
    u[0] = cvt_pk_bf16(a.x, a.y);
    u[1] = cvt_pk_bf16(a.z, a.w);
    u[2] = cvt_pk_bf16(b.x, b.y);
    u[3] = cvt_pk_bf16(b.z, b.w);
    return __builtin_bit_cast(bf16x8, u);
}

// -------- kernel 1 (swapped): Pre0[t][b][n] = b0[n] + sum_k x[b][t][k]*Wx0[n][k]
__global__ __launch_bounds__(256) void k_pre(const float* __restrict__ x,
                                             const float* __restrict__ Wx0,
                                             const float* __restrict__ b0,
                                             unsigned short* __restrict__ Pre0) {
    const int t  = blockIdx.x;
    const int bc = blockIdx.y;
    const int w  = threadIdx.x >> 6;
    const int l  = threadIdx.x & 63;
    const int lr = l & 15, lg = l >> 4;

    bf16x8 af[4];
    const float* xrow = x + ((size_t)(bc * 16 + lr) * T_ + t) * DIN_ + lg * 8;
#pragma unroll
    for (int kk = 0; kk < 4; kk++) af[kk] = ld8f_bf(xrow + kk * 32);

    unsigned short* op = Pre0 + ((size_t)t * B_ + bc * 16 + lr) * H_;

#pragma unroll
    for (int i = 0; i < 4; i++) {
        const int n0 = (w + 4 * i) * 16;
        const float* wrow = Wx0 + (size_t)(n0 + lr) * DIN_ + lg * 8;
        bf16x8 bfr[4];
#pragma unroll
        for (int kk = 0; kk < 4; kk++) bfr[kk] = ld8f_bf(wrow + kk * 32);
        float4 bv = *(const float4*)&b0[n0 + lg * 4];
        f32x4 acc = { bv.x, bv.y, bv.z, bv.w };
#pragma unroll
        for (int kk = 0; kk < 4; kk++)
            acc = __builtin_amdgcn_mfma_f32_16x16x32_bf16(bfr[kk], af[kk], acc, 0, 0, 0);
        u32x2 pk;
        pk[0] = cvt_pk_bf16(acc[0], acc[1]);
        pk[1] = cvt_pk_bf16(acc[2], acc[3]);
        *(u32x2*)&op[n0 + lg * 4] = pk;
    }
}

// ---- scan0 body: layer-0 recurrence over t in [t0,t1). 8 waves x 32 n,
// M=1 broadcast-LDS. Initial state from h0in (t0==0) or the h0n stream.
static __device__ void scan0_body(int b, int tid,
                                  const float* __restrict__ h0in,
                                  const float* __restrict__ Wh0,
                                  const unsigned short* __restrict__ Pre0,
                                  unsigned short* __restrict__ h0n,
                                  int t0, int t1) {
    __shared__ __align__(16) unsigned short h0s[2][256];

    const int w  = tid >> 6, l = tid & 63;
    const int lr = l & 15, lg = l >> 4;
    const int n0 = w * 32;

    bf16x8 wh0f[2][8];   // W[n0+u*16+lr][kk*32+lg*8 .. +7]
#pragma unroll
    for (int u = 0; u < 2; u++) {
        const int n = n0 + u * 16 + lr;
#pragma unroll
        for (int kk = 0; kk < 8; kk++)
            wh0f[u][kk] = ld8f_bf(Wh0 + (size_t)n * H_ + kk * 32 + lg * 8);
    }

    if (tid < 256)
        h0s[0][tid] = (t0 == 0) ? f2bf(h0in[(size_t)b * H_ + tid])
                                : h0n[((size_t)b * T_ + t0 - 1) * H_ + tid];

    const unsigned short* prep = Pre0 + ((size_t)t0 * B_ + b) * H_ + n0 + lg * 4;
    u32x2 pv[2];
#pragma unroll
    for (int u = 0; u < 2; u++) pv[u] = *(const u32x2*)(prep + u * 16);
    prep += B_ * H_;

    unsigned short* op = h0n + ((size_t)b * T_ + t0) * H_ + n0 + lg * 4;

    __syncthreads();

    int cur = 0;
    for (int t = t0; t < t1; t++) {
        const int nxt = cur ^ 1;
        f32x4 a[2][2];   // [n-tile][k-half]
#pragma unroll
        for (int u = 0; u < 2; u++) {
            a[u][0][0] = bfbits_lo(pv[u][0]); a[u][0][1] = bfbits_hi(pv[u][0]);
            a[u][0][2] = bfbits_lo(pv[u][1]); a[u][0][3] = bfbits_hi(pv[u][1]);
            a[u][1] = (f32x4){0.0f, 0.0f, 0.0f, 0.0f};
        }
        // prefetch next Pre0 (over-read at t1-1 stays outside concurrent writers)
#pragma unroll
        for (int u = 0; u < 2; u++) pv[u] = *(const u32x2*)(prep + u * 16);
        prep += B_ * H_;
#pragma unroll
        for (int kk = 0; kk < 4; kk++) {
            bf16x8 s0 = __builtin_bit_cast(bf16x8, *(const u16x8*)&h0s[cur][kk * 32 + lg * 8]);
            bf16x8 s1 = __builtin_bit_cast(bf16x8, *(const u16x8*)&h0s[cur][(kk + 4) * 32 + lg * 8]);
#pragma unroll
            for (int u = 0; u < 2; u++) {
                a[u][0] = __builtin_amdgcn_mfma_f32_16x16x32_bf16(wh0f[u][kk],     s0, a[u][0], 0, 0, 0);
                a[u][1] = __builtin_amdgcn_mfma_f32_16x16x32_bf16(wh0f[u][kk + 4], s1, a[u][1], 0, 0, 0);
            }
        }
#pragma unroll
        for (int u = 0; u < 2; u++) {
            f32x4 h = a[u][0] + a[u][1];
            u32x2 pk;
            pk[0] = cvt_pk_bf16(tanh_fast(h[0]), tanh_fast(h[1]));
            pk[1] = cvt_pk_bf16(tanh_fast(h[2]), tanh_fast(h[3]));
            if (lr == 0) {
                *(u32x2*)&h0s[nxt][n0 + u * 16 + lg * 4] = pk;
                *(u32x2*)(op + u * 16) = pk;
            }
        }
        op += H_;
        BAR_LDS();
        cur = nxt;
    }
}

// ---- scan1 body: time-batched P1 + layer-1 recurrence over t in [t0,t1).
// Initial h1 from h0in (t0==0) or the H1 stream (bf16, bit-identical).
static __device__ void scan1_body(int b, int tid,
                                  const float* __restrict__ h0in,
                                  const float* __restrict__ Wx1,
                                  const float* __restrict__ Wh1,
                                  const float* __restrict__ b1,
                                  const unsigned short* __restrict__ h0n,
                                  unsigned short* __restrict__ H1,
                                  int t0, int t1) {
    __shared__ __align__(16) unsigned short h1s[2][256];
    __shared__ __align__(16) float p1lds[16][264];

    const int w  = tid >> 6, l = tid & 63;
    const int lr = l & 15, lg = l >> 4;
    const int n0 = w * 32;

    bf16x8 wx1f[2][8], wh1f[2][8];
#pragma unroll
    for (int u = 0; u < 2; u++) {
        const int n = n0 + u * 16 + lr;
#pragma unroll
        for (int kk = 0; kk < 8; kk++) {
            wx1f[u][kk] = ld8f_bf(Wx1 + (size_t)n * H_ + kk * 32 + lg * 8);
            wh1f[u][kk] = ld8f_bf(Wh1 + (size_t)n * H_ + kk * 32 + lg * 8);
        }
    }
    float4 b1q[2];
#pragma unroll
    for (int u = 0; u < 2; u++) b1q[u] = *(const float4*)&b1[n0 + u * 16 + lg * 4];

    if (tid < 256)
        h1s[0][tid] = (t0 == 0) ? f2bf(h0in[(size_t)(B_ + b) * H_ + tid])
                                : H1[((size_t)(t0 - 1) * B_ + b) * H_ + tid];

    const unsigned short* hp = h0n + (size_t)b * T_ * H_;
    unsigned short* yp = H1 + (size_t)b * H_ + n0 + lg * 4;

    __syncthreads();

    int cur = 0;
    for (int tc = t0 / 16; tc < t1 / 16; tc++) {
        // ---- phase A: p1 tile (32 n x 16 t) for this wave
        f32x4 p[2][2];
#pragma unroll
        for (int u = 0; u < 2; u++) {
            p[u][0] = (f32x4){ b1q[u].x, b1q[u].y, b1q[u].z, b1q[u].w };
            p[u][1] = (f32x4){0.0f, 0.0f, 0.0f, 0.0f};
        }
        const unsigned short* hrow = hp + (size_t)(tc * 16 + lr) * H_ + lg * 8;
#pragma unroll
        for (int kk = 0; kk < 4; kk++) {
            bf16x8 s0 = __builtin_bit_cast(bf16x8, *(const u16x8*)(hrow + kk * 32));
            bf16x8 s1 = __builtin_bit_cast(bf16x8, *(const u16x8*)(hrow + (kk + 4) * 32));
#pragma unroll
            for (int u = 0; u < 2; u++) {
                p[u][0] = __builtin_amdgcn_mfma_f32_16x16x32_bf16(wx1f[u][kk],     s0, p[u][0], 0, 0, 0);
                p[u][1] = __builtin_amdgcn_mfma_f32_16x16x32_bf16(wx1f[u][kk + 4], s1, p[u][1], 0, 0, 0);
            }
        }
#pragma unroll
        for (int u = 0; u < 2; u++) {
            f32x4 pp = p[u][0] + p[u][1];
            *(f32x4*)&p1lds[lr][n0 + u * 16 + lg * 4] = pp;
        }
        // no barrier: each wave reads back only its own columns

        // ---- phase B: 16 sequential layer-1 steps
        for (int ti = 0; ti < 16; ti++) {
            const int nxt = cur ^ 1;
            f32x4 d[2][2];
#pragma unroll
            for (int u = 0; u < 2; u++) {
                d[u][0] = *(const f32x4*)&p1lds[ti][n0 + u * 16 + lg * 4];
                d[u][1] = (f32x4){0.0f, 0.0f, 0.0f, 0.0f};
            }
#pragma unroll
            for (int kk = 0; kk < 4; kk++) {
                bf16x8 s0 = __builtin_bit_cast(bf16x8, *(const u16x8*)&h1s[cur][kk * 32 + lg * 8]);
                bf16x8 s1 = __builtin_bit_cast(bf16x8, *(const u16x8*)&h1s[cur][(kk + 4) * 32 + lg * 8]);
#pragma unroll
                for (int u = 0; u < 2; u++) {
                    d[u][0] = __builtin_amdgcn_mfma_f32_16x16x32_bf16(wh1f[u][kk],     s0, d[u][0], 0, 0, 0);
                    d[u][1] = __builtin_amdgcn_mfma_f32_16x16x32_bf16(wh1f[u][kk + 4], s1, d[u][1], 0, 0, 0);
                }
            }
#pragma unroll
            for (int u = 0; u < 2; u++) {
                f32x4 hh = d[u][0] + d[u][1];
                u32x2 pk;
                pk[0] = cvt_pk_bf16(tanh_fast(hh[0]), tanh_fast(hh[1]));
                pk[1] = cvt_pk_bf16(tanh_fast(hh[2]), tanh_fast(hh[3]));
                if (lr == 0) {
                    *(u32x2*)&h1s[nxt][n0 + u * 16 + lg * 4] = pk;
                    *(u32x2*)(yp + (size_t)(tc * 16 + ti) * B_ * H_ + u * 16) = pk;
                }
            }
            BAR_LDS();
            cur = nxt;
        }
    }
}

// -------- kernel 2: pipelined mixed scan. 128 blocks x 512 threads.
// Blocks 0..63:  scan0 over [s, s+CH)      (producer chunk k)
// Blocks 64..127: scan1 over [s-CH, s)     (consumer chunk k-1)
// Ranges are DISJOINT in Pre0/h0n/H1 -> no races, no fences; the chunk
// dependency is carried by stream-ordered kernel launches.
__global__ __launch_bounds__(512)
void k_scan_mix(const float* __restrict__ h0in,
                const float* __restrict__ Wh0,
                const float* __restrict__ Wx1,
                const float* __restrict__ Wh1,
                const float* __restrict__ b1,
                const unsigned short* __restrict__ Pre0,
                unsigned short* __restrict__ h0n,
                unsigned short* __restrict__ H1,
                int s) {
    const int role = blockIdx.x >> 6;
    const int b    = blockIdx.x & 63;
    const int tid  = threadIdx.x;
    if (role == 0) {
        int t0 = s, t1 = s + CH_;
        if (t0 >= T_) return;
        if (t1 > T_) t1 = T_;
        scan0_body(b, tid, h0in, Wh0, Pre0, h0n, t0, t1);
    } else {
        int t0 = s - CH_, t1 = s;
        if (t1 <= 0) return;
        if (t0 < 0) t0 = 0;
        scan1_body(b, tid, h0in, Wx1, Wh1, b1, h0n, H1, t0, t1);
    }
}

// -------- kernel 3 (swapped): Y[b][t][d] = bout[d] + sum_k H1[t][b][k]*Wout[d][k]
__global__ __launch_bounds__(256) void k_out(const unsigned short* __restrict__ H1,
                                             const float* __restrict__ Wout,
                                             const float* __restrict__ bout,
                                             float* __restrict__ out) {
    const int t  = blockIdx.x;
    const int bc = blockIdx.y;
    const int w  = threadIdx.x >> 6;
    const int l  = threadIdx.x & 63;
    const int lr = l & 15, lg = l >> 4;

    bf16x8 af[8];
    const unsigned short* hrow = H1 + ((size_t)t * B_ + bc * 16 + lr) * H_ + lg * 8;
#pragma unroll
    for (int kk = 0; kk < 8; kk++)
        af[kk] = __builtin_bit_cast(bf16x8, *(const u16x8*)(hrow + kk * 32));

#pragma unroll
    for (int i = 0; i < 2; i++) {
        const int n0 = (w + 4 * i) * 16;
        const float* wrow = Wout + (size_t)(n0 + lr) * H_ + lg * 8;
        float4 bv = *(const float4*)&bout[n0 + lg * 4];
        f32x4 acc = { bv.x, bv.y, bv.z, bv.w };
#pragma unroll
        for (int kk = 0; kk < 8; kk++) {
            bf16x8 bfr = ld8f_bf(wrow + kk * 32);
            acc = __builtin_amdgcn_mfma_f32_16x16x32_bf16(bfr, af[kk], acc, 0, 0, 0);
        }
        *(f32x4*)&out[((size_t)(bc * 16 + lr) * T_ + t) * DOUT_ + n0 + lg * 4] = acc;
    }
}

extern "C" void kernel_launch(void* const* d_in, const int* in_sizes, int n_in,
                              void* d_out, int out_size, void* d_ws, size_t ws_size,
                              hipStream_t stream) {
    const float* x    = (const float*)d_in[0];
    const float* h0   = (const float*)d_in[1];
    const float* Wx0  = (const float*)d_in[2];
    const float* Wh0  = (const float*)d_in[3];
    const float* b0   = (const float*)d_in[4];
    const float* Wx1  = (const float*)d_in[5];
    const float* Wh1  = (const float*)d_in[6];
    const float* b1   = (const float*)d_in[7];
    const float* Wout = (const float*)d_in[8];
    const float* bout = (const float*)d_in[9];
    float* out = (float*)d_out;

    // ws: region A (64MB) = Pre0, progressively overwritten by H1 exactly one
    //     chunk behind the scan0 read front (disjoint per launch).
    //     region B (64MB) = h0n stream [b][t][n] bf16.
    unsigned short* Pre0 = (unsigned short*)d_ws;
    unsigned short* h0n  = Pre0 + (size_t)T_ * B_ * H_;
    unsigned short* H1   = Pre0;

    k_pre<<<dim3(T_, B_ / 16), 256, 0, stream>>>(x, Wx0, b0, Pre0);
    for (int s = 0; s <= T_; s += CH_)
        k_scan_mix<<<dim3(2 * B_), 512, 0, stream>>>(h0, Wh0, Wx1, Wh1, b1,
                                                     Pre0, h0n, H1, s);
    k_out<<<dim3(T_, B_ / 16), 256, 0, stream>>>(H1, Wout, bout, out);
}